// Round 7
// baseline (87.735 us; speedup 1.0000x reference)
//
#include <hip/hip_runtime.h>
#include <math.h>

#define B 512
#define N 256
#define E 1024
#define D 256
#define H 256
#define C 8
#define U 64

// ---------------------------------------------------------------------------
// Mask dtype sniffing: flag 0 = int32 words, 1 = byte-packed bool, 2 = float32
// ---------------------------------------------------------------------------
__device__ __forceinline__ float mask_val(const void* m, long i, int flag) {
    if (flag == 1) return ((const unsigned char*)m)[i] ? 1.f : 0.f;
    if (flag == 2) return (((const float*)m)[i] != 0.f) ? 1.f : 0.f;
    return ((const int*)m)[i] ? 1.f : 0.f;
}

// block-wide sum reduction (256 threads)
__device__ __forceinline__ float block_sum(float v, float* red) {
    int t = threadIdx.x;
    red[t] = v; __syncthreads();
    for (int s = 128; s > 0; s >>= 1) {
        if (t < s) red[t] += red[t + s];
        __syncthreads();
    }
    float r = red[0]; __syncthreads();
    return r;
}

// ---------------------------------------------------------------------------
// k_h: per-batch trunk, 2 rows/block, 512 threads, grid=256.
// Block 0 sniffs the mask dtype into *flag.
// ---------------------------------------------------------------------------
__global__ __launch_bounds__(512) void k_h(
    const float* __restrict__ feat,
    const float* __restrict__ Wc1, const float* __restrict__ bc1,
    const float* __restrict__ Wc2, const float* __restrict__ bc2,
    const float* __restrict__ Wn1, const float* __restrict__ bn1,
    const float* __restrict__ We1, const float* __restrict__ be1,
    const float* __restrict__ Wg,  const float* __restrict__ bg,
    const float* __restrict__ margin, const float* __restrict__ brisk,
    const unsigned int* __restrict__ amask_words,
    float* __restrict__ base_n, float* __restrict__ base_e,
    float* __restrict__ out_gate, int* __restrict__ flag)
{
    __shared__ __align__(16) float sF[2][256];
    __shared__ __align__(16) float sH[2][256];
    __shared__ float red[512];
    __shared__ int cls0, cls1;

    int t = threadIdx.x;
    int w = t >> 8;        // 0/1: row in P1/P2, matrix in P3
    int c = t & 255;
    int b0 = blockIdx.x * 2;
    int b = b0 + w;

    if (blockIdx.x == 0) {
        if (t == 0) { cls0 = 0; cls1 = 0; }
        __syncthreads();
        if (t < 256) {
            unsigned int wd = amask_words[t];
            if (wd != 0u && wd != 1u) {
                if (wd == 0x3f800000u) atomicOr(&cls1, 1);
                else                   atomicOr(&cls0, 1);
            }
        }
        __syncthreads();
        if (t == 0) *flag = cls0 ? 1 : (cls1 ? 2 : 0);
    }

    sF[w][c] = feat[(long)b * D + c];
    __syncthreads();

    // ---- P1: relu(feat @ Wc1 + bc1) -> sH ----
    {
        float acc[4] = {bc1[c], 0.f, 0.f, 0.f};
        const float* Wp = Wc1 + c;
        for (int d0 = 0; d0 < D; d0 += 16) {
            float wv[16];
            #pragma unroll
            for (int k = 0; k < 16; k++) wv[k] = Wp[(long)(d0 + k) * H];
            #pragma unroll
            for (int k = 0; k < 16; k++)
                acc[k & 3] = fmaf(sF[w][d0 + k], wv[k], acc[k & 3]);
        }
        sH[w][c] = fmaxf((acc[0] + acc[1]) + (acc[2] + acc[3]), 0.f);
    }
    __syncthreads();

    // ---- P2: h = relu(A @ Wc2 + bc2) -> sF ----
    {
        float acc[4] = {bc2[c], 0.f, 0.f, 0.f};
        const float* Wp = Wc2 + c;
        for (int d0 = 0; d0 < H; d0 += 16) {
            float wv[16];
            #pragma unroll
            for (int k = 0; k < 16; k++) wv[k] = Wp[(long)(d0 + k) * H];
            #pragma unroll
            for (int k = 0; k < 16; k++)
                acc[k & 3] = fmaf(sH[w][d0 + k], wv[k], acc[k & 3]);
        }
        float a = fmaxf((acc[0] + acc[1]) + (acc[2] + acc[3]), 0.f);
        __syncthreads();
        sF[w][c] = a;                 // sF now holds h for both rows
    }
    __syncthreads();

    // ---- gate per row ----
    red[t] = sF[w][c] * Wg[c];
    __syncthreads();
    for (int s = 128; s > 0; s >>= 1) {
        if (c < s) red[t] += red[t + s];
        __syncthreads();
    }
    if (c == 0) {
        float lg = 1.f / (1.f + expf(-(red[t] + bg[0])));
        out_gate[b] = ((margin[b] < 0.2f) || (brisk[b] > 0.6f) || (lg > 0.5f)) ? 1.f : 0.f;
    }

    // ---- P3: base_n / base_e (thread-half = matrix, both rows) ----
    {
        const float* W3  = w ? (We1 + c) : (Wn1 + c);
        float bias       = w ? be1[c]    : bn1[c];
        float* dst       = w ? base_e    : base_n;
        float aA[2] = {bias, 0.f};
        float aB[2] = {bias, 0.f};
        for (int d0 = 0; d0 < H; d0 += 16) {
            float wv[16];
            #pragma unroll
            for (int k = 0; k < 16; k++) wv[k] = W3[(long)(d0 + k) * H];
            #pragma unroll
            for (int k = 0; k < 16; k++) {
                aA[k & 1] = fmaf(sF[0][d0 + k], wv[k], aA[k & 1]);
                aB[k & 1] = fmaf(sF[1][d0 + k], wv[k], aB[k & 1]);
            }
        }
        dst[(long)b0 * H + c]       = aA[0] + aA[1];
        dst[(long)(b0 + 1) * H + c] = aB[0] + aB[1];
    }
}

// ---------------------------------------------------------------------------
// k_ne: item-split. Blocks [0,512): node row b, 1 node/thread, FULL 256-j
// loop, fused centering/top-2/margin/riskbase (whole row in block).
// Blocks [512,1536): edge row-half (b=(bid-512)>>1, half=&1), 2 edges/thread,
// full j-loop, writes FINAL refined_edge. No atomics, no partial buffers.
// Weight+base pack [256][12] in LDS; j-loop = 3 uniform ds_read_b128 + FMAs.
// ---------------------------------------------------------------------------
__global__ __launch_bounds__(256) void k_ne(
    const float* __restrict__ cs, const float* __restrict__ coords,
    const float* __restrict__ unc, const int* __restrict__ actions,
    const void* __restrict__ amask,
    const float* __restrict__ Wn1, const float* __restrict__ Wn2,
    const float* __restrict__ bn2, const float* __restrict__ base_n,
    const float* __restrict__ es, const int* __restrict__ edges,
    const void* __restrict__ emask,
    const float* __restrict__ We1, const float* __restrict__ We2,
    const float* __restrict__ be2, const float* __restrict__ base_e,
    const float* __restrict__ gate, const int* __restrict__ flagp,
    float* __restrict__ out0, float* __restrict__ out1,
    float* __restrict__ out2, float* __restrict__ out3,
    float* __restrict__ riskbase)
{
    __shared__ __align__(16) float smem[3072 + 2304]; // pack + (sC | red/ridx)
    float* pack = smem;
    int t = threadIdx.x;
    int flag = *flagp;

    if (blockIdx.x < B) {
        // ================= NODE row =================
        int b = blockIdx.x;
        float g = gate[b];
        float am = mask_val(amask, (long)b * N + t, flag);
        float csv = cs[(long)b * N + t];
        int a = actions[(long)b * N + t];
        a = min(max(a, 0), U - 1);
        float ug = unc[(long)b * U + a];

        float raw;
        if (g != 0.f) {
            // stage pack: [j][0..9]=Wn1 extras, [10]=Wn2, [11]=base_n[b]
            {
                float* p = pack + t * 12;
                #pragma unroll
                for (int k = 0; k < 10; k++) p[k] = Wn1[(long)(H + k) * H + t];
                p[10] = Wn2[t];
                p[11] = base_n[(long)b * H + t];
            }
            const float4* cp = (const float4*)(coords + ((long)b * N + t) * C);
            float4 c0 = cp[0], c1 = cp[1];
            float f0 = c0.x, f1 = c0.y, f2 = c0.z, f3 = c0.w;
            float f4 = c1.x, f5 = c1.y, f6 = c1.z, f7 = c1.w;
            float f8 = csv, f9 = ug;
            float acc = bn2[0];
            __syncthreads();

            #pragma unroll 4
            for (int j = 0; j < H; j++) {
                const float* pj = pack + j * 12;
                float4 wa = *(const float4*)(pj);
                float4 wb = *(const float4*)(pj + 4);
                float4 wc = *(const float4*)(pj + 8);
                float zA = fmaf(f0, wa.x, wc.w);     // base
                zA = fmaf(f1, wa.y, zA);
                zA = fmaf(f2, wa.z, zA);
                zA = fmaf(f3, wa.w, zA);
                float zB = f4 * wb.x;
                zB = fmaf(f5, wb.y, zB);
                zB = fmaf(f6, wb.z, zB);
                zB = fmaf(f7, wb.w, zB);
                zB = fmaf(f8, wc.x, zB);
                zB = fmaf(f9, wc.y, zB);
                acc = fmaf(fmaxf(zA + zB, 0.f), wc.z, acc);
            }
            raw = (csv + g * 0.1f * (acc * am)) * am;
            __syncthreads();   // pack region reads done
        } else {
            raw = csv * am;
        }

        // ---- fused finalization ----
        float* red = smem + 3072;
        int* ridx = (int*)(smem + 3072 + 256);

        float sum = block_sum(raw, red);
        float cnt = block_sum(am, red);
        float denom = fmaxf(cnt, 1.f);
        float rs = (raw - sum / denom) * am;
        out0[(long)b * N + t] = rs;

        float masked = (am != 0.f) ? rs : -1e9f;

        red[t] = masked; ridx[t] = t; __syncthreads();
        for (int s = 128; s > 0; s >>= 1) {
            if (t < s) {
                float o = red[t + s]; int oi = ridx[t + s];
                if (o > red[t] || (o == red[t] && oi < ridx[t])) { red[t] = o; ridx[t] = oi; }
            }
            __syncthreads();
        }
        float v1 = red[0]; int i1 = ridx[0]; __syncthreads();

        red[t] = (t == i1) ? -1e9f : masked; __syncthreads();
        for (int s = 128; s > 0; s >>= 1) {
            if (t < s) red[t] = fmaxf(red[t], red[t + s]);
            __syncthreads();
        }
        float v2 = red[0]; __syncthreads();
        float rmargin = v1 - v2;

        float su = block_sum(ug * am, red);

        if (t == 0) {
            out1[b] = rmargin;
            out3[b] = (float)i1;
            float sig = 1.f / (1.f + expf(rmargin));   // sigmoid(-margin)
            riskbase[b] = sig + 0.1f * (su / denom);
        }
    } else {
        // ================= EDGE row-half =================
        int eb = blockIdx.x - B;
        int b = eb >> 1, half = eb & 1;
        float g = gate[b];
        int e0 = half * 512 + t;

        if (g == 0.f) {
            #pragma unroll
            for (int q = 0; q < 2; q++) {
                long idx = (long)b * E + e0 + 256 * q;
                float em = mask_val(emask, idx, flag);
                out2[idx] = es[idx] * em;
            }
            return;
        }

        float* sC = smem + 3072;   // [256][9] padded coords

        // stage coords (stride 9: gcd(9,32)=1 -> gather banks well spread)
        {
            const float4* g4 = (const float4*)(coords + (long)b * N * C);
            float4 c0 = g4[t * 2], c1 = g4[t * 2 + 1];
            float* dst = sC + t * 9;
            dst[0] = c0.x; dst[1] = c0.y; dst[2] = c0.z; dst[3] = c0.w;
            dst[4] = c1.x; dst[5] = c1.y; dst[6] = c1.z; dst[7] = c1.w;
        }
        // stage pack: [j][0..8]=We1 extras k=0..8, [9]=We2,
        // [10]=base_e[b]+w9 (emf==1 fold), [11]=pad
        {
            float* p = pack + t * 12;
            #pragma unroll
            for (int k = 0; k < 9; k++) p[k] = We1[(long)(H + k) * H + t];
            p[9] = We2[t];
            p[10] = base_e[(long)b * H + t] + We1[(long)(H + 9) * H + t];
            p[11] = 0.f;
        }
        float b2v = be2[0];
        __syncthreads();

        float f[2][9], acc[2], emv[2];
        #pragma unroll
        for (int q = 0; q < 2; q++) {
            long idx = (long)b * E + e0 + 256 * q;
            int2 ev = ((const int2*)edges)[idx];
            int s0 = min(max(ev.x, 0), N - 1);
            int d0 = min(max(ev.y, 0), N - 1);
            const float* cs0 = sC + s0 * 9;
            const float* cd0 = sC + d0 * 9;
            #pragma unroll
            for (int k = 0; k < 8; k++) f[q][k] = cd0[k] - cs0[k];
            f[q][8] = es[idx];
            emv[q] = mask_val(emask, idx, flag);
            acc[q] = b2v;
        }

        #pragma unroll 4
        for (int j = 0; j < H; j++) {
            const float* pj = pack + j * 12;
            float4 wa = *(const float4*)(pj);
            float4 wb = *(const float4*)(pj + 4);
            float4 wc = *(const float4*)(pj + 8);
            #pragma unroll
            for (int q = 0; q < 2; q++) {
                float zA = fmaf(f[q][0], wa.x, wc.z);   // base (+w9 fold)
                zA = fmaf(f[q][1], wa.y, zA);
                zA = fmaf(f[q][2], wa.z, zA);
                zA = fmaf(f[q][3], wa.w, zA);
                float zB = f[q][4] * wb.x;
                zB = fmaf(f[q][5], wb.y, zB);
                zB = fmaf(f[q][6], wb.z, zB);
                zB = fmaf(f[q][7], wb.w, zB);
                zB = fmaf(f[q][8], wc.x, zB);
                acc[q] = fmaf(fmaxf(zA + zB, 0.f), wc.y, acc[q]);
            }
        }

        #pragma unroll
        for (int q = 0; q < 2; q++) {
            long idx = (long)b * E + e0 + 256 * q;
            out2[idx] = (emv[q] != 0.f) ? (f[q][8] + g * 0.1f * acc[q]) : 0.f;
        }
    }
}

// ---------------------------------------------------------------------------
// k_fin: edge rows only — mean/var of refined_edge -> evar.
// ---------------------------------------------------------------------------
__global__ __launch_bounds__(256) void k_fin(
    const void* __restrict__ emask, const int* __restrict__ flagp,
    const float* __restrict__ out2, float* __restrict__ evar)
{
    __shared__ float red[256];
    int t = threadIdx.x;
    int b = blockIdx.x;
    int flag = *flagp;

    float x[4], em[4];
    float S1 = 0.f, ce = 0.f;
    #pragma unroll
    for (int q = 0; q < 4; q++) {
        long idx = (long)b * E + t + 256 * q;
        x[q] = out2[idx];
        em[q] = mask_val(emask, idx, flag);
        S1 += x[q]; ce += em[q];
    }
    float S1t = block_sum(S1, red);
    float cet = block_sum(ce, red);
    float mean = S1t / fmaxf(cet, 1.f);
    float v = 0.f;
    #pragma unroll
    for (int q = 0; q < 4; q++) {
        float dd = x[q] - mean;
        v = fmaf(em[q] * dd, dd, v);
    }
    float vt = block_sum(v, red);
    if (t == 0) {
        float var = vt / fmaxf(cet, 1.f);
        evar[b] = (cet > 1.f) ? var : 0.f;
    }
}

// ---------------------------------------------------------------------------
// k_risk: out4 = clip(riskbase + 0.2*evar, 0, 1)
// ---------------------------------------------------------------------------
__global__ __launch_bounds__(256) void k_risk(
    const float* __restrict__ riskbase, const float* __restrict__ evar,
    float* __restrict__ out4)
{
    int b = blockIdx.x * 256 + threadIdx.x;
    float r = riskbase[b] + 0.2f * evar[b];
    out4[b] = fminf(fmaxf(r, 0.f), 1.f);
}

// ---------------------------------------------------------------------------
extern "C" void kernel_launch(void* const* d_in, const int* in_sizes, int n_in,
                              void* d_out, int out_size, void* d_ws, size_t ws_size,
                              hipStream_t stream) {
    const float* feat   = (const float*)d_in[0];
    const float* cs     = (const float*)d_in[1];
    const float* marg   = (const float*)d_in[2];
    const float* brisk  = (const float*)d_in[3];
    const float* es     = (const float*)d_in[4];
    const float* coords = (const float*)d_in[5];
    const float* unc    = (const float*)d_in[6];
    const float* Wc1    = (const float*)d_in[7];
    const float* bc1    = (const float*)d_in[8];
    const float* Wc2    = (const float*)d_in[9];
    const float* bc2    = (const float*)d_in[10];
    const float* Wn1    = (const float*)d_in[11];
    const float* bn1    = (const float*)d_in[12];
    const float* Wn2    = (const float*)d_in[13];
    const float* bn2    = (const float*)d_in[14];
    const float* We1    = (const float*)d_in[15];
    const float* be1    = (const float*)d_in[16];
    const float* We2    = (const float*)d_in[17];
    const float* be2    = (const float*)d_in[18];
    const float* Wg     = (const float*)d_in[19];
    const float* bg     = (const float*)d_in[20];
    const void*  amask  = d_in[21];
    const void*  emask  = d_in[22];
    const int*   actions= (const int*)d_in[23];
    const int*   edges  = (const int*)d_in[24];

    float* out0 = (float*)d_out;           // refined_scores (B,N)
    float* out1 = out0 + (long)B * N;      // refined_margin (B,)
    float* out2 = out1 + B;                // refined_edge (B,E)
    float* out3 = out2 + (long)B * E;      // top_idx (B,) as float
    float* out4 = out3 + B;                // refined_risk (B,)
    float* out5 = out4 + B;                // refine_gate (B,)

    float* base_n   = (float*)d_ws;                  // B*H
    float* base_e   = base_n + (long)B * H;          // B*H
    float* riskbase = base_e + (long)B * H;          // B
    float* evar     = riskbase + B;                  // B
    int*   flag     = (int*)(evar + B);

    k_h<<<B / 2, 512, 0, stream>>>(feat, Wc1, bc1, Wc2, bc2, Wn1, bn1, We1, be1,
                                   Wg, bg, marg, brisk,
                                   (const unsigned int*)amask,
                                   base_n, base_e, out5, flag);
    k_ne<<<B + 2 * B, 256, 0, stream>>>(cs, coords, unc, actions, amask,
                                        Wn1, Wn2, bn2, base_n,
                                        es, edges, emask,
                                        We1, We2, be2, base_e,
                                        out5, flag,
                                        out0, out1, out2, out3, riskbase);
    k_fin<<<B, 256, 0, stream>>>(emask, flag, out2, evar);
    k_risk<<<2, 256, 0, stream>>>(riskbase, evar, out4);
}